// Round 11
// baseline (286.199 us; speedup 1.0000x reference)
//
#include <hip/hip_runtime.h>
#include <hip/hip_bf16.h>
#include <math.h>

// B=4, N=2048, C=768, H=12, D=64; tokens = 8192

typedef short bf16x8 __attribute__((ext_vector_type(8)));
typedef float f32x4 __attribute__((ext_vector_type(4)));
typedef float f32x16 __attribute__((ext_vector_type(16)));

static __device__ __forceinline__ unsigned short f2bf(float f) {
    unsigned int u = __float_as_uint(f);
    unsigned int r = u + 0x7fff + ((u >> 16) & 1);   // RNE
    return (unsigned short)(r >> 16);
}
static __device__ __forceinline__ unsigned int pack2(float a, float b) {
    return (unsigned int)f2bf(a) | ((unsigned int)f2bf(b) << 16);
}
// HW packed f32x2 -> bf16x2 (RNE), single VALU op
static __device__ __forceinline__ unsigned int cvtpk(float a, float b) {
    unsigned int r;
    asm("v_cvt_pk_bf16_f32 %0, %1, %2" : "=v"(r) : "v"(a), "v"(b));
    return r;
}
static __device__ __forceinline__ void gl_lds16(const void* g, void* l) {
    __builtin_amdgcn_global_load_lds(
        (const __attribute__((address_space(1))) unsigned int*)g,
        (__attribute__((address_space(3))) unsigned int*)l, 16, 0, 0);
}

// ---------------- converter: x fp32 -> bf16 ----------------
__global__ __launch_bounds__(256) void convx_kernel(
    const float* __restrict__ in, unsigned short* __restrict__ out)
{
    size_t i = ((size_t)blockIdx.x * 256 + threadIdx.x) * 8;
    float4 a = *(const float4*)&in[i];
    float4 b = *(const float4*)&in[i + 4];
    uint4 o = make_uint4(pack2(a.x, a.y), pack2(a.z, a.w), pack2(b.x, b.y), pack2(b.z, b.w));
    *(uint4*)&out[i] = o;
}

// ---------------- converter: transpose fp32 weights -> bf16 [cols][768], both W sets ----
__global__ __launch_bounds__(256) void convT_kernel(
    const float* __restrict__ Wq, const float* __restrict__ Wkv, const float* __restrict__ Wp,
    unsigned short* __restrict__ WqkvT, unsigned short* __restrict__ WprjT)
{
    __shared__ char tb[8192];
    const int bx = blockIdx.x, k0 = blockIdx.y * 64;
    const float* src; int ld; int cbase; unsigned short* out; int c0;
    if (bx < 36) {
        c0 = bx * 64; out = WqkvT;
        if (c0 < 768) { src = Wq;  ld = 768;  cbase = c0; }
        else          { src = Wkv; ld = 1536; cbase = c0 - 768; }
    } else {
        c0 = (bx - 36) * 64; out = WprjT; src = Wp; ld = 768; cbase = c0;
    }
    const int t = threadIdx.x;
    const int kl = t >> 2, cq = (t & 3) * 16;
    #pragma unroll
    for (int jj = 0; jj < 4; ++jj) {
        float4 v = *(const float4*)&src[(size_t)(k0 + kl) * ld + cbase + cq + jj * 4];
        float vv[4] = {v.x, v.y, v.z, v.w};
        #pragma unroll
        for (int je = 0; je < 4; ++je) {
            int c = cq + jj * 4 + je;
            *(unsigned short*)(tb + c * 128 + ((kl * 2) ^ ((c & 7) << 4))) = f2bf(vv[je]);
        }
    }
    __syncthreads();
    const int cl = t >> 2, u2 = (t & 3) * 2;
    uint4 r0 = *(const uint4*)(tb + cl * 128 + ((u2 ^ (cl & 7)) << 4));
    uint4 r1 = *(const uint4*)(tb + cl * 128 + (((u2 + 1) ^ (cl & 7)) << 4));
    size_t ob = (size_t)(c0 + cl) * 768 + k0 + (t & 3) * 16;
    *(uint4*)&out[ob] = r0;
    *(uint4*)&out[ob + 8] = r1;
}

// ---------------- Kernel: QKV bf16 MFMA GEMM + bias + l2norm + scatter ----------------
// Q is pre-scaled by scale*log2(e) so attention can use raw exp2.
__global__ __launch_bounds__(256) void qkv_gemm_kernel(
    const unsigned short* __restrict__ xb, const unsigned short* __restrict__ WT,
    const float* __restrict__ bq, const float* __restrict__ bkv,
    const float* __restrict__ scale,
    unsigned short* __restrict__ Qb, unsigned short* __restrict__ Kb,
    unsigned short* __restrict__ Vtb)
{
    __shared__ char lds[32768] __attribute__((aligned(16)));

    const int ct = blockIdx.x;
    const int row0 = blockIdx.y * 128;
    const int tid = threadIdx.x;
    const int w = tid >> 6, l = tid & 63;
    const int g = l >> 4, ln = l & 15;
    const int wr = w >> 1, wc = w & 1;
    const int col0 = ct * 128;

    const int srow = (w & 1) * 64 + (l >> 3);
    const int su = ((l & 7) ^ (l >> 3)) * 16;
    const char* s = (w < 2)
        ? (const char*)xb + (size_t)(row0 + srow) * 1536 + su
        : (const char*)WT + (size_t)(col0 + srow) * 1536 + su;
    char* dbase = lds + ((w >= 2) ? 16384 : 0) + (w & 1) * 8192;

    f32x4 acc[4][4];
    #pragma unroll
    for (int m = 0; m < 4; ++m)
        #pragma unroll
        for (int n = 0; n < 4; ++n) acc[m][n] = (f32x4){0.f, 0.f, 0.f, 0.f};

    const int arow = (wr * 64 + ln) * 128;
    const int brow = 16384 + (wc * 64 + ln) * 128;
    const int x0 = ((0 + g) ^ (ln & 7)) * 16;
    const int x1 = ((4 + g) ^ (ln & 7)) * 16;

    for (int ks = 0; ks < 12; ++ks) {
        __syncthreads();
        #pragma unroll
        for (int j = 0; j < 8; ++j)
            gl_lds16(s + (size_t)j * 8 * 1536, dbase + j * 1024);
        s += 128;
        __syncthreads();
        #pragma unroll
        for (int kc = 0; kc < 2; ++kc) {
            const int xo = kc ? x1 : x0;
            bf16x8 af[4], bfr[4];
            #pragma unroll
            for (int m = 0; m < 4; ++m) af[m] = *(const bf16x8*)(lds + arow + m * 2048 + xo);
            #pragma unroll
            for (int n = 0; n < 4; ++n) bfr[n] = *(const bf16x8*)(lds + brow + n * 2048 + xo);
            #pragma unroll
            for (int m = 0; m < 4; ++m)
                #pragma unroll
                for (int n = 0; n < 4; ++n)
                    acc[m][n] = __builtin_amdgcn_mfma_f32_16x16x32_bf16(af[m], bfr[n], acc[m][n], 0, 0, 0);
        }
    }

    const int co = col0 + wc * 64 + ln;
    float bv[4];
    #pragma unroll
    for (int n = 0; n < 4; ++n) {
        int c = co + n * 16;
        bv[n] = (c < 768) ? bq[c] : bkv[c - 768];
    }
    const int region = ct / 6;
    const int h = (ct % 6) * 2 + wc;

    if (region < 2) {
        unsigned short* dst = (region == 0) ? Qb : Kb;
        const float post = (region == 0) ? scale[0] * 1.4426950408889634f : 1.0f;
        #pragma unroll
        for (int m = 0; m < 4; ++m) {
            #pragma unroll
            for (int n = 0; n < 4; ++n)
                #pragma unroll
                for (int r = 0; r < 4; ++r) acc[m][n][r] += bv[n];
            #pragma unroll
            for (int r = 0; r < 4; ++r) {
                float ss = 0.f;
                #pragma unroll
                for (int n = 0; n < 4; ++n) ss += acc[m][n][r] * acc[m][n][r];
                ss += __shfl_xor(ss, 1); ss += __shfl_xor(ss, 2);
                ss += __shfl_xor(ss, 4); ss += __shfl_xor(ss, 8);
                float inv = post / fmaxf(sqrtf(ss), 1e-12f);
                int t = row0 + wr * 64 + m * 16 + g * 4 + r;
                int b = t >> 11, nt = t & 2047;
                size_t base = ((size_t)(b * 12 + h) * 2048 + nt) * 64 + ln;
                #pragma unroll
                for (int n = 0; n < 4; ++n)
                    dst[base + n * 16] = f2bf(acc[m][n][r] * inv);
            }
        }
    } else {
        char* tb = lds + w * 8192;
        __syncthreads();
        #pragma unroll
        for (int m = 0; m < 4; ++m)
            #pragma unroll
            for (int n = 0; n < 4; ++n)
                #pragma unroll
                for (int r = 0; r < 4; ++r) {
                    int d = n * 16 + ln;
                    int tok = m * 16 + g * 4 + r;
                    *(unsigned short*)(tb + d * 128 + ((tok * 2) ^ ((d & 7) << 4))) =
                        f2bf(acc[m][n][r] + bv[n]);
                }
        __syncthreads();
        const int t0 = row0 + wr * 64;
        const int b = t0 >> 11, n0 = t0 & 2047;
        #pragma unroll
        for (int i = 0; i < 8; ++i) {
            int d = i * 8 + (l >> 3);
            uint4 v = *(const uint4*)(tb + d * 128 + (((l & 7) ^ (d & 7)) << 4));
            *(uint4*)&Vtb[((size_t)(b * 12 + h) * 64 + d) * 2048 + n0 + (l & 7) * 8] = v;
        }
    }
}

// ---------------- Kernel: MFMA flash attention, 32x32 MFMA, padded-stride LDS (132B) ----
// grid (16, 48) XCD-remapped, block 256 = 4 waves, 32 q-rows/wave, KT=64.
// Reg-staging (T14): global->reg issued before compute, ds_write after. No XOR swizzle:
// 132B row stride makes 32-row b128 reads conflict-free (bank = row + col/4 mod 32).
__global__ __launch_bounds__(256, 3) void attn_kernel(
    const unsigned short* __restrict__ Qg, const unsigned short* __restrict__ Kg,
    const unsigned short* __restrict__ Vtg,
    unsigned short* __restrict__ O)
{
    // K buf0 @0, K buf1 @8448, V buf0 @16896, V buf1 @25344; total 33792
    __shared__ char lds[33792] __attribute__((aligned(16)));

    const int bid = blockIdx.y * 16 + blockIdx.x;
    const int swzb = (bid & 7) * 96 + (bid >> 3);
    const int bh = swzb >> 4;
    const int q0 = (swzb & 15) * 128;

    const int tid = threadIdx.x;
    const int w  = tid >> 6;
    const int l  = tid & 63;
    const int lo = l & 31;
    const int hi = l >> 5;

    // staging: wave w owns rows w*16..w*16+15 (2 chunks of 8 rows), plain linear cols
    const int srow = w * 16 + (l >> 3);
    const int scol = (l & 7) * 16;
    const char* kG = (const char*)Kg  + ((size_t)bh * 2048 + srow) * 128 + scol;   // +t*8192, chunk +1024
    const char* vG = (const char*)Vtg + ((size_t)bh * 64   + srow) * 4096 + scol;  // +t*128, chunk +32768
    const int wOff = srow * 132 + scol;   // LDS write base, chunk +1056

    uint4 kr0, kr1, vr0, vr1;
    auto issue = [&](int t) {
        const char* kp = kG + (size_t)t * 8192;
        const char* vp = vG + (size_t)t * 128;
        kr0 = *(const uint4*)(kp);
        kr1 = *(const uint4*)(kp + 1024);
        vr0 = *(const uint4*)(vp);
        vr1 = *(const uint4*)(vp + 32768);
    };
    auto writeb = [&](int buf) {
        char* kb = lds + buf * 8448 + wOff;
        char* vb = lds + 16896 + buf * 8448 + wOff;
        *(uint4*)kb = kr0; *(uint4*)(kb + 1056) = kr1;
        *(uint4*)vb = vr0; *(uint4*)(vb + 1056) = vr1;
    };

    // Q B-frags (whole kernel): col=lo -> qrow, k=hi*8+j -> feature
    bf16x8 qf[4];
    {
        const unsigned short* qp = Qg + ((size_t)bh * 2048 + q0 + w * 32 + lo) * 64 + hi * 8;
        qf[0] = *(const bf16x8*)(qp);
        qf[1] = *(const bf16x8*)(qp + 16);
        qf[2] = *(const bf16x8*)(qp + 32);
        qf[3] = *(const bf16x8*)(qp + 48);
    }

    const int rowb = lo * 132;            // padded stride: conflict-free reads
    int coff[4];
    #pragma unroll
    for (int c = 0; c < 4; ++c) coff[c] = c * 32 + hi * 16;

    f32x16 oacc0, oacc1;
    #pragma unroll
    for (int r = 0; r < 16; ++r) { oacc0[r] = 0.f; oacc1[r] = 0.f; }
    float rs = 0.f;

    const f32x16 zero16 = {0.f,0.f,0.f,0.f,0.f,0.f,0.f,0.f,0.f,0.f,0.f,0.f,0.f,0.f,0.f,0.f};

    auto compute = [&](const int OFF) {
        const char* Kb = lds + OFF;
        const char* Vb = lds + 16896 + OFF;

        // ---- S^T = K Q^T : D[row=k][col=q], two 32-k blocks (upper rows at +4224) ----
        f32x16 s0, s1;
        __builtin_amdgcn_s_setprio(1);
        s0 = __builtin_amdgcn_mfma_f32_32x32x16_bf16(*(const bf16x8*)(Kb + rowb + coff[0]), qf[0], zero16, 0, 0, 0);
        s0 = __builtin_amdgcn_mfma_f32_32x32x16_bf16(*(const bf16x8*)(Kb + rowb + coff[1]), qf[1], s0, 0, 0, 0);
        s0 = __builtin_amdgcn_mfma_f32_32x32x16_bf16(*(const bf16x8*)(Kb + rowb + coff[2]), qf[2], s0, 0, 0, 0);
        s0 = __builtin_amdgcn_mfma_f32_32x32x16_bf16(*(const bf16x8*)(Kb + rowb + coff[3]), qf[3], s0, 0, 0, 0);
        s1 = __builtin_amdgcn_mfma_f32_32x32x16_bf16(*(const bf16x8*)(Kb + 4224 + rowb + coff[0]), qf[0], zero16, 0, 0, 0);
        s1 = __builtin_amdgcn_mfma_f32_32x32x16_bf16(*(const bf16x8*)(Kb + 4224 + rowb + coff[1]), qf[1], s1, 0, 0, 0);
        s1 = __builtin_amdgcn_mfma_f32_32x32x16_bf16(*(const bf16x8*)(Kb + 4224 + rowb + coff[2]), qf[2], s1, 0, 0, 0);
        s1 = __builtin_amdgcn_mfma_f32_32x32x16_bf16(*(const bf16x8*)(Kb + 4224 + rowb + coff[3]), qf[3], s1, 0, 0, 0);
        __builtin_amdgcn_s_setprio(0);

        // ---- p = exp2(s) (Q pre-scaled); per-lane partial row-sum; cvt_pk pack ----
        unsigned int pcur[16];
        #pragma unroll
        for (int kb = 0; kb < 2; ++kb) {
            float e[16];
            #pragma unroll
            for (int r = 0; r < 16; ++r)
                e[r] = __builtin_amdgcn_exp2f(kb ? s1[r] : s0[r]);
            float t = 0.f;
            #pragma unroll
            for (int r = 0; r < 16; r += 4) t += (e[r] + e[r+1]) + (e[r+2] + e[r+3]);
            rs += t;
            #pragma unroll
            for (int ksb = 0; ksb < 2; ++ksb) {
                pcur[kb*8 + ksb*4 + 0] = cvtpk(e[ksb*8 + 0], e[ksb*8 + 1]);
                pcur[kb*8 + ksb*4 + 1] = cvtpk(e[ksb*8 + 2], e[ksb*8 + 3]);
                pcur[kb*8 + ksb*4 + 2] = cvtpk(e[ksb*8 + 4], e[ksb*8 + 5]);
                pcur[kb*8 + ksb*4 + 3] = cvtpk(e[ksb*8 + 6], e[ksb*8 + 7]);
            }
        }

        // ---- PV: permlane32_swap builds A-frag; V fragments from padded LDS ----
        #pragma unroll
        for (int kb = 0; kb < 2; ++kb) {
            #pragma unroll
            for (int ksb = 0; ksb < 2; ++ksb) {
                const int base = kb*8 + ksb*4;
                const int ks = kb*2 + ksb;
                unsigned int uA0 = pcur[base + 0];
                unsigned int uA1 = pcur[base + 1];
                unsigned int uB0 = pcur[base + 2];
                unsigned int uB1 = pcur[base + 3];
                asm("v_permlane32_swap_b32 %0, %1" : "+v"(uA0), "+v"(uB0));
                asm("v_permlane32_swap_b32 %0, %1" : "+v"(uA1), "+v"(uB1));
                unsigned int fw[4] = {uA0, uA1, uB0, uB1};
                bf16x8 pa;
                __builtin_memcpy(&pa, fw, 16);
                __builtin_amdgcn_s_setprio(1);
                bf16x8 v0 = *(const bf16x8*)(Vb + rowb + coff[ks]);
                bf16x8 v1 = *(const bf16x8*)(Vb + 4224 + rowb + coff[ks]);
                oacc0 = __builtin_amdgcn_mfma_f32_32x32x16_bf16(pa, v0, oacc0, 0, 0, 0);
                oacc1 = __builtin_amdgcn_mfma_f32_32x32x16_bf16(pa, v1, oacc1, 0, 0, 0);
                __builtin_amdgcn_s_setprio(0);
            }
        }
    };

    // prologue: tile 0 -> buf0
    issue(0); writeb(0);
    __syncthreads();

    #pragma unroll 1
    for (int it = 0; it < 16; ++it) {
        issue(2 * it + 1);
        compute(0);
        writeb(1);
        __syncthreads();
        if (it < 15) issue(2 * it + 2);
        compute(8448);
        if (it < 15) writeb(0);
        __syncthreads();
    }

    // epilogue: reduce row-sums across lane halves, normalize, store bf16 token-major
    float rsv = rs;
    rsv += __shfl_xor(rsv, 32);
    const int b = bh / 12, h = bh % 12;
    #pragma unroll
    for (int r = 0; r < 16; ++r) {
        const int qr = (r & 3) + 8 * (r >> 2) + 4 * hi;
        float inv = 1.0f / __shfl(rsv, qr);
        size_t base = ((size_t)(b * 2048 + q0 + w * 32 + qr)) * 768 + h * 64 + lo;
        O[base]      = f2bf(oacc0[r] * inv);
        O[base + 32] = f2bf(oacc1[r] * inv);
    }
}

// ---------------- Kernel: proj bf16 MFMA GEMM + bias -> fp32 out ----------------
__global__ __launch_bounds__(256) void proj_gemm_kernel(
    const unsigned short* __restrict__ Ob, const unsigned short* __restrict__ WT,
    const float* __restrict__ bp, float* __restrict__ out)
{
    __shared__ char lds[32768] __attribute__((aligned(16)));

    const int row0 = blockIdx.y * 128;
    const int col0 = blockIdx.x * 128;
    const int tid = threadIdx.x;
    const int w = tid >> 6, l = tid & 63;
    const int g = l >> 4, ln = l & 15;
    const int wr = w >> 1, wc = w & 1;

    const int srow = (w & 1) * 64 + (l >> 3);
    const int su = ((l & 7) ^ (l >> 3)) * 16;
    const char* s = (w < 2)
        ? (const char*)Ob + (size_t)(row0 + srow) * 1536 + su
        : (const char*)WT + (size_t)(col0 + srow) * 1536 + su;
    char* dbase = lds + ((w >= 2) ? 16384 : 0) + (w & 1) * 8192;

    f32x4 acc[4][4];
    #pragma unroll
    for (int m = 0; m < 4; ++m)
        #pragma unroll
        for (int n = 0; n < 4; ++n) acc[m][n] = (f32x4){0.f, 0.f, 0.f, 0.f};

    const int arow = (wr * 64 + ln) * 128;
    const int brow = 16384 + (wc * 64 + ln) * 128;
    const int x0 = ((0 + g) ^ (ln & 7)) * 16;
    const int x1 = ((4 + g) ^ (ln & 7)) * 16;

    for (int ks = 0; ks < 12; ++ks) {
        __syncthreads();
        #pragma unroll
        for (int j = 0; j < 8; ++j)
            gl_lds16(s + (size_t)j * 8 * 1536, dbase + j * 1024);
        s += 128;
        __syncthreads();
        #pragma unroll
        for (int kc = 0; kc < 2; ++kc) {
            const int xo = kc ? x1 : x0;
            bf16x8 af[4], bfr[4];
            #pragma unroll
            for (int m = 0; m < 4; ++m) af[m] = *(const bf16x8*)(lds + arow + m * 2048 + xo);
            #pragma unroll
            for (int n = 0; n < 4; ++n) bfr[n] = *(const bf16x8*)(lds + brow + n * 2048 + xo);
            #pragma unroll
            for (int m = 0; m < 4; ++m)
                #pragma unroll
                for (int n = 0; n < 4; ++n)
                    acc[m][n] = __builtin_amdgcn_mfma_f32_16x16x32_bf16(af[m], bfr[n], acc[m][n], 0, 0, 0);
        }
    }

    const int co = col0 + wc * 64 + ln;
    float bv[4];
    #pragma unroll
    for (int n = 0; n < 4; ++n) bv[n] = bp[co + n * 16];
    #pragma unroll
    for (int m = 0; m < 4; ++m)
        #pragma unroll
        for (int r = 0; r < 4; ++r) {
            int t = row0 + wr * 64 + m * 16 + g * 4 + r;
            #pragma unroll
            for (int n = 0; n < 4; ++n)
                out[(size_t)t * 768 + co + n * 16] = acc[m][n][r] + bv[n];
        }
}

extern "C" void kernel_launch(void* const* d_in, const int* in_sizes, int n_in,
                              void* d_out, int out_size, void* d_ws, size_t ws_size,
                              hipStream_t stream) {
    const float* x     = (const float*)d_in[0];
    const float* Wq    = (const float*)d_in[1];
    const float* bq    = (const float*)d_in[2];
    const float* Wkv   = (const float*)d_in[3];
    const float* bkv   = (const float*)d_in[4];
    const float* Wp    = (const float*)d_in[5];
    const float* bp    = (const float*)d_in[6];
    const float* scale = (const float*)d_in[7];
    float* out = (float*)d_out;

    unsigned short* ws = (unsigned short*)d_ws;
    const size_t SZ = (size_t)4 * 12 * 2048 * 64;     // 6,291,456
    unsigned short* xbw   = ws;
    unsigned short* WqkvT = xbw + SZ;
    unsigned short* WprjT = WqkvT + (size_t)2304 * 768;
    unsigned short* Qw    = WprjT + (size_t)768 * 768;
    unsigned short* Kw    = Qw + SZ;
    unsigned short* Vtw   = Kw + SZ;
    unsigned short* Ow    = Vtw + SZ;

    convx_kernel<<<3072, 256, 0, stream>>>(x, xbw);
    convT_kernel<<<dim3(48, 12), 256, 0, stream>>>(Wq, Wkv, Wp, WqkvT, WprjT);
    qkv_gemm_kernel<<<dim3(18, 64), 256, 0, stream>>>(xbw, WqkvT, bq, bkv, scale, Qw, Kw, Vtw);
    attn_kernel<<<dim3(16, 48), 256, 0, stream>>>(Qw, Kw, Vtw, Ow);
    proj_gemm_kernel<<<dim3(6, 64), 256, 0, stream>>>(Ow, WprjT, bp, out);
}

// Round 12
// 142.910 us; speedup vs baseline: 2.0027x; 2.0027x over previous
//
#include <hip/hip_runtime.h>
#include <hip/hip_bf16.h>
#include <math.h>

// B=4, N=2048, C=768, H=12, D=64; tokens = 8192

typedef short bf16x8 __attribute__((ext_vector_type(8)));
typedef float f32x4 __attribute__((ext_vector_type(4)));
typedef float f32x16 __attribute__((ext_vector_type(16)));

static __device__ __forceinline__ unsigned short f2bf(float f) {
    unsigned int u = __float_as_uint(f);
    unsigned int r = u + 0x7fff + ((u >> 16) & 1);   // RNE
    return (unsigned short)(r >> 16);
}
static __device__ __forceinline__ unsigned int pack2(float a, float b) {
    return (unsigned int)f2bf(a) | ((unsigned int)f2bf(b) << 16);
}
// HW packed f32x2 -> bf16x2 (RNE), single VALU op
static __device__ __forceinline__ unsigned int cvtpk(float a, float b) {
    unsigned int r;
    asm("v_cvt_pk_bf16_f32 %0, %1, %2" : "=v"(r) : "v"(a), "v"(b));
    return r;
}
static __device__ __forceinline__ void gl_lds16(const void* g, void* l) {
    __builtin_amdgcn_global_load_lds(
        (const __attribute__((address_space(1))) unsigned int*)g,
        (__attribute__((address_space(3))) unsigned int*)l, 16, 0, 0);
}

// ---------------- converter: x fp32 -> bf16 ----------------
__global__ __launch_bounds__(256) void convx_kernel(
    const float* __restrict__ in, unsigned short* __restrict__ out)
{
    size_t i = ((size_t)blockIdx.x * 256 + threadIdx.x) * 8;
    float4 a = *(const float4*)&in[i];
    float4 b = *(const float4*)&in[i + 4];
    uint4 o = make_uint4(pack2(a.x, a.y), pack2(a.z, a.w), pack2(b.x, b.y), pack2(b.z, b.w));
    *(uint4*)&out[i] = o;
}

// ---------------- converter: transpose fp32 weights -> bf16 [cols][768], both W sets ----
__global__ __launch_bounds__(256) void convT_kernel(
    const float* __restrict__ Wq, const float* __restrict__ Wkv, const float* __restrict__ Wp,
    unsigned short* __restrict__ WqkvT, unsigned short* __restrict__ WprjT)
{
    __shared__ char tb[8192];
    const int bx = blockIdx.x, k0 = blockIdx.y * 64;
    const float* src; int ld; int cbase; unsigned short* out; int c0;
    if (bx < 36) {
        c0 = bx * 64; out = WqkvT;
        if (c0 < 768) { src = Wq;  ld = 768;  cbase = c0; }
        else          { src = Wkv; ld = 1536; cbase = c0 - 768; }
    } else {
        c0 = (bx - 36) * 64; out = WprjT; src = Wp; ld = 768; cbase = c0;
    }
    const int t = threadIdx.x;
    const int kl = t >> 2, cq = (t & 3) * 16;
    #pragma unroll
    for (int jj = 0; jj < 4; ++jj) {
        float4 v = *(const float4*)&src[(size_t)(k0 + kl) * ld + cbase + cq + jj * 4];
        float vv[4] = {v.x, v.y, v.z, v.w};
        #pragma unroll
        for (int je = 0; je < 4; ++je) {
            int c = cq + jj * 4 + je;
            *(unsigned short*)(tb + c * 128 + ((kl * 2) ^ ((c & 7) << 4))) = f2bf(vv[je]);
        }
    }
    __syncthreads();
    const int cl = t >> 2, u2 = (t & 3) * 2;
    uint4 r0 = *(const uint4*)(tb + cl * 128 + ((u2 ^ (cl & 7)) << 4));
    uint4 r1 = *(const uint4*)(tb + cl * 128 + (((u2 + 1) ^ (cl & 7)) << 4));
    size_t ob = (size_t)(c0 + cl) * 768 + k0 + (t & 3) * 16;
    *(uint4*)&out[ob] = r0;
    *(uint4*)&out[ob + 8] = r1;
}

// ---------------- Kernel: QKV bf16 MFMA GEMM + bias + l2norm + scatter ----------------
// Q is pre-scaled by scale*log2(e) so attention can use raw exp2.
__global__ __launch_bounds__(256) void qkv_gemm_kernel(
    const unsigned short* __restrict__ xb, const unsigned short* __restrict__ WT,
    const float* __restrict__ bq, const float* __restrict__ bkv,
    const float* __restrict__ scale,
    unsigned short* __restrict__ Qb, unsigned short* __restrict__ Kb,
    unsigned short* __restrict__ Vtb)
{
    __shared__ char lds[32768] __attribute__((aligned(16)));

    const int ct = blockIdx.x;
    const int row0 = blockIdx.y * 128;
    const int tid = threadIdx.x;
    const int w = tid >> 6, l = tid & 63;
    const int g = l >> 4, ln = l & 15;
    const int wr = w >> 1, wc = w & 1;
    const int col0 = ct * 128;

    const int srow = (w & 1) * 64 + (l >> 3);
    const int su = ((l & 7) ^ (l >> 3)) * 16;
    const char* s = (w < 2)
        ? (const char*)xb + (size_t)(row0 + srow) * 1536 + su
        : (const char*)WT + (size_t)(col0 + srow) * 1536 + su;
    char* dbase = lds + ((w >= 2) ? 16384 : 0) + (w & 1) * 8192;

    f32x4 acc[4][4];
    #pragma unroll
    for (int m = 0; m < 4; ++m)
        #pragma unroll
        for (int n = 0; n < 4; ++n) acc[m][n] = (f32x4){0.f, 0.f, 0.f, 0.f};

    const int arow = (wr * 64 + ln) * 128;
    const int brow = 16384 + (wc * 64 + ln) * 128;
    const int x0 = ((0 + g) ^ (ln & 7)) * 16;
    const int x1 = ((4 + g) ^ (ln & 7)) * 16;

    for (int ks = 0; ks < 12; ++ks) {
        __syncthreads();
        #pragma unroll
        for (int j = 0; j < 8; ++j)
            gl_lds16(s + (size_t)j * 8 * 1536, dbase + j * 1024);
        s += 128;
        __syncthreads();
        #pragma unroll
        for (int kc = 0; kc < 2; ++kc) {
            const int xo = kc ? x1 : x0;
            bf16x8 af[4], bfr[4];
            #pragma unroll
            for (int m = 0; m < 4; ++m) af[m] = *(const bf16x8*)(lds + arow + m * 2048 + xo);
            #pragma unroll
            for (int n = 0; n < 4; ++n) bfr[n] = *(const bf16x8*)(lds + brow + n * 2048 + xo);
            #pragma unroll
            for (int m = 0; m < 4; ++m)
                #pragma unroll
                for (int n = 0; n < 4; ++n)
                    acc[m][n] = __builtin_amdgcn_mfma_f32_16x16x32_bf16(af[m], bfr[n], acc[m][n], 0, 0, 0);
        }
    }

    const int co = col0 + wc * 64 + ln;
    float bv[4];
    #pragma unroll
    for (int n = 0; n < 4; ++n) {
        int c = co + n * 16;
        bv[n] = (c < 768) ? bq[c] : bkv[c - 768];
    }
    const int region = ct / 6;
    const int h = (ct % 6) * 2 + wc;

    if (region < 2) {
        unsigned short* dst = (region == 0) ? Qb : Kb;
        const float post = (region == 0) ? scale[0] * 1.4426950408889634f : 1.0f;
        #pragma unroll
        for (int m = 0; m < 4; ++m) {
            #pragma unroll
            for (int n = 0; n < 4; ++n)
                #pragma unroll
                for (int r = 0; r < 4; ++r) acc[m][n][r] += bv[n];
            #pragma unroll
            for (int r = 0; r < 4; ++r) {
                float ss = 0.f;
                #pragma unroll
                for (int n = 0; n < 4; ++n) ss += acc[m][n][r] * acc[m][n][r];
                ss += __shfl_xor(ss, 1); ss += __shfl_xor(ss, 2);
                ss += __shfl_xor(ss, 4); ss += __shfl_xor(ss, 8);
                float inv = post / fmaxf(sqrtf(ss), 1e-12f);
                int t = row0 + wr * 64 + m * 16 + g * 4 + r;
                int b = t >> 11, nt = t & 2047;
                size_t base = ((size_t)(b * 12 + h) * 2048 + nt) * 64 + ln;
                #pragma unroll
                for (int n = 0; n < 4; ++n)
                    dst[base + n * 16] = f2bf(acc[m][n][r] * inv);
            }
        }
    } else {
        char* tb = lds + w * 8192;
        __syncthreads();
        #pragma unroll
        for (int m = 0; m < 4; ++m)
            #pragma unroll
            for (int n = 0; n < 4; ++n)
                #pragma unroll
                for (int r = 0; r < 4; ++r) {
                    int d = n * 16 + ln;
                    int tok = m * 16 + g * 4 + r;
                    *(unsigned short*)(tb + d * 128 + ((tok * 2) ^ ((d & 7) << 4))) =
                        f2bf(acc[m][n][r] + bv[n]);
                }
        __syncthreads();
        const int t0 = row0 + wr * 64;
        const int b = t0 >> 11, n0 = t0 & 2047;
        #pragma unroll
        for (int i = 0; i < 8; ++i) {
            int d = i * 8 + (l >> 3);
            uint4 v = *(const uint4*)(tb + d * 128 + (((l & 7) ^ (d & 7)) << 4));
            *(uint4*)&Vtb[((size_t)(b * 12 + h) * 64 + d) * 2048 + n0 + (l & 7) * 8] = v;
        }
    }
}

// ---------------- Kernel: MFMA flash attention, 32x32 MFMA, P-in-registers (R8 best) ----
// grid (16, 48) XCD-remapped, block 256 = 4 waves, 32 q-rows/wave, KT=64.
// S^T = mfma(K, Q): lane holds col q = l&31; P->PV A-frag built with cvt_pk + permlane32_swap.
__global__ __launch_bounds__(256, 3) void attn_kernel(
    const unsigned short* __restrict__ Qg, const unsigned short* __restrict__ Kg,
    const unsigned short* __restrict__ Vtg,
    unsigned short* __restrict__ O)
{
    __shared__ char lds[32768] __attribute__((aligned(16)));
    // K dbuf: 0/8192 ; Vt dbuf: 16384/24576

    const int bid = blockIdx.y * 16 + blockIdx.x;
    const int swzb = (bid & 7) * 96 + (bid >> 3);
    const int bh = swzb >> 4;
    const int q0 = (swzb & 15) * 128;

    const int tid = threadIdx.x;
    const int w  = tid >> 6;
    const int l  = tid & 63;
    const int lo = l & 31;
    const int hi = l >> 5;

    // staging (pre-swizzled source): wave w stages rows w*16..w*16+15 of each 64-row tile
    const int srow = w * 16 + (l >> 3);
    const int su   = ((l & 7) ^ (l >> 3)) * 16;
    const char* kS = (const char*)Kg  + ((size_t)bh * 2048 + srow) * 128 + su;   // += 8192/tile
    const char* vS = (const char*)Vtg + ((size_t)bh * 64   + srow) * 4096 + su;  // += 128/tile
    char* kD = lds + w * 2048;
    char* vD = lds + 16384 + w * 2048;

    // Q B-frags (whole kernel): col=lo -> qrow, k=hi*8+j -> feature
    bf16x8 qf[4];
    {
        const unsigned short* qp = Qg + ((size_t)bh * 2048 + q0 + w * 32 + lo) * 64 + hi * 8;
        qf[0] = *(const bf16x8*)(qp);
        qf[1] = *(const bf16x8*)(qp + 16);
        qf[2] = *(const bf16x8*)(qp + 32);
        qf[3] = *(const bf16x8*)(qp + 48);
    }

    // LDS read offsets: row (x*32+lo)*128, col (c*32 + hi*16) ^ swz   (c = f-step or k-step)
    const int swz = (lo & 7) << 4;
    const int rowb = lo * 128;
    int coff[4];
    #pragma unroll
    for (int c = 0; c < 4; ++c) coff[c] = (c * 32 + hi * 16) ^ swz;

    f32x16 oacc0, oacc1;
    #pragma unroll
    for (int r = 0; r < 16; ++r) { oacc0[r] = 0.f; oacc1[r] = 0.f; }
    float rs = 0.f;

    const f32x16 zero16 = {0.f,0.f,0.f,0.f,0.f,0.f,0.f,0.f,0.f,0.f,0.f,0.f,0.f,0.f,0.f,0.f};

    auto compute = [&](const int OFF) {
        const char* Kb = lds + OFF;
        const char* Vb = lds + 16384 + OFF;

        // ---- S^T = K Q^T : D[row=k][col=q], two 32-k blocks ----
        f32x16 s0, s1;
        __builtin_amdgcn_s_setprio(1);
        s0 = __builtin_amdgcn_mfma_f32_32x32x16_bf16(*(const bf16x8*)(Kb + rowb + coff[0]), qf[0], zero16, 0, 0, 0);
        s0 = __builtin_amdgcn_mfma_f32_32x32x16_bf16(*(const bf16x8*)(Kb + rowb + coff[1]), qf[1], s0, 0, 0, 0);
        s0 = __builtin_amdgcn_mfma_f32_32x32x16_bf16(*(const bf16x8*)(Kb + rowb + coff[2]), qf[2], s0, 0, 0, 0);
        s0 = __builtin_amdgcn_mfma_f32_32x32x16_bf16(*(const bf16x8*)(Kb + rowb + coff[3]), qf[3], s0, 0, 0, 0);
        s1 = __builtin_amdgcn_mfma_f32_32x32x16_bf16(*(const bf16x8*)(Kb + 4096 + rowb + coff[0]), qf[0], zero16, 0, 0, 0);
        s1 = __builtin_amdgcn_mfma_f32_32x32x16_bf16(*(const bf16x8*)(Kb + 4096 + rowb + coff[1]), qf[1], s1, 0, 0, 0);
        s1 = __builtin_amdgcn_mfma_f32_32x32x16_bf16(*(const bf16x8*)(Kb + 4096 + rowb + coff[2]), qf[2], s1, 0, 0, 0);
        s1 = __builtin_amdgcn_mfma_f32_32x32x16_bf16(*(const bf16x8*)(Kb + 4096 + rowb + coff[3]), qf[3], s1, 0, 0, 0);
        __builtin_amdgcn_s_setprio(0);

        // ---- p = exp2(s) (Q pre-scaled); per-lane partial row-sum ----
        #pragma unroll
        for (int r = 0; r < 16; ++r) s0[r] = __builtin_amdgcn_exp2f(s0[r]);
        #pragma unroll
        for (int r = 0; r < 16; ++r) s1[r] = __builtin_amdgcn_exp2f(s1[r]);
        float t0 = 0.f, t1 = 0.f;
        #pragma unroll
        for (int r = 0; r < 16; ++r) { t0 += s0[r]; t1 += s1[r]; }
        rs += t0 + t1;

        // ---- PV: build A-frag in regs (cvt_pk + permlane32_swap), MFMA against V ----
        #pragma unroll
        for (int kb = 0; kb < 2; ++kb) {
            const f32x16 ec = kb ? s1 : s0;
            #pragma unroll
            for (int ksb = 0; ksb < 2; ++ksb) {
                const int ks = kb * 2 + ksb;
                const int rqA = ksb * 2, rqB = rqA + 1;
                unsigned int uA0 = cvtpk(ec[rqA * 4 + 0], ec[rqA * 4 + 1]);
                unsigned int uA1 = cvtpk(ec[rqA * 4 + 2], ec[rqA * 4 + 3]);
                unsigned int uB0 = cvtpk(ec[rqB * 4 + 0], ec[rqB * 4 + 1]);
                unsigned int uB1 = cvtpk(ec[rqB * 4 + 2], ec[rqB * 4 + 3]);
                // (d',s') = ({d.lo,s.lo},{d.hi,s.hi}): d'=word t, s'=word t+2
                asm("v_permlane32_swap_b32 %0, %1" : "+v"(uA0), "+v"(uB0));
                asm("v_permlane32_swap_b32 %0, %1" : "+v"(uA1), "+v"(uB1));
                unsigned int fw[4] = {uA0, uA1, uB0, uB1};
                bf16x8 pa;
                __builtin_memcpy(&pa, fw, 16);
                __builtin_amdgcn_s_setprio(1);
                bf16x8 v0 = *(const bf16x8*)(Vb + rowb + coff[ks]);
                bf16x8 v1 = *(const bf16x8*)(Vb + 4096 + rowb + coff[ks]);
                oacc0 = __builtin_amdgcn_mfma_f32_32x32x16_bf16(pa, v0, oacc0, 0, 0, 0);
                oacc1 = __builtin_amdgcn_mfma_f32_32x32x16_bf16(pa, v1, oacc1, 0, 0, 0);
                __builtin_amdgcn_s_setprio(0);
            }
        }
    };

    // prologue: tile 0 -> buf0
    gl_lds16(kS, kD);          gl_lds16(kS + 1024, kD + 1024);
    gl_lds16(vS, vD);          gl_lds16(vS + 32768, vD + 1024);
    kS += 8192; vS += 128;
    __syncthreads();

    #pragma unroll 1
    for (int it = 0; it < 16; ++it) {
        gl_lds16(kS, kD + 8192);          gl_lds16(kS + 1024, kD + 9216);
        gl_lds16(vS, vD + 8192);          gl_lds16(vS + 32768, vD + 9216);
        kS += 8192; vS += 128;
        compute(0);
        __syncthreads();
        if (it < 15) {
            gl_lds16(kS, kD);          gl_lds16(kS + 1024, kD + 1024);
            gl_lds16(vS, vD);          gl_lds16(vS + 32768, vD + 1024);
            kS += 8192; vS += 128;
        }
        compute(8192);
        __syncthreads();
    }

    // epilogue: reduce row-sums across lane halves, normalize, store bf16 token-major
    float rsv = rs;
    rsv += __shfl_xor(rsv, 32);          // full denom for q = lo (both halves)
    const int b = bh / 12, h = bh % 12;
    #pragma unroll
    for (int r = 0; r < 16; ++r) {
        const int qr = (r & 3) + 8 * (r >> 2) + 4 * hi;
        float inv = 1.0f / __shfl(rsv, qr);
        size_t base = ((size_t)(b * 2048 + q0 + w * 32 + qr)) * 768 + h * 64 + lo;
        O[base]      = f2bf(oacc0[r] * inv);
        O[base + 32] = f2bf(oacc1[r] * inv);
    }
}

// ---------------- Kernel: proj bf16 MFMA GEMM + bias -> fp32 out ----------------
__global__ __launch_bounds__(256) void proj_gemm_kernel(
    const unsigned short* __restrict__ Ob, const unsigned short* __restrict__ WT,
    const float* __restrict__ bp, float* __restrict__ out)
{
    __shared__ char lds[32768] __attribute__((aligned(16)));

    const int row0 = blockIdx.y * 128;
    const int col0 = blockIdx.x * 128;
    const int tid = threadIdx.x;
    const int w = tid >> 6, l = tid & 63;
    const int g = l >> 4, ln = l & 15;
    const int wr = w >> 1, wc = w & 1;

    const int srow = (w & 1) * 64 + (l >> 3);
    const int su = ((l & 7) ^ (l >> 3)) * 16;
    const char* s = (w < 2)
        ? (const char*)Ob + (size_t)(row0 + srow) * 1536 + su
        : (const char*)WT + (size_t)(col0 + srow) * 1536 + su;
    char* dbase = lds + ((w >= 2) ? 16384 : 0) + (w & 1) * 8192;

    f32x4 acc[4][4];
    #pragma unroll
    for (int m = 0; m < 4; ++m)
        #pragma unroll
        for (int n = 0; n < 4; ++n) acc[m][n] = (f32x4){0.f, 0.f, 0.f, 0.f};

    const int arow = (wr * 64 + ln) * 128;
    const int brow = 16384 + (wc * 64 + ln) * 128;
    const int x0 = ((0 + g) ^ (ln & 7)) * 16;
    const int x1 = ((4 + g) ^ (ln & 7)) * 16;

    for (int ks = 0; ks < 12; ++ks) {
        __syncthreads();
        #pragma unroll
        for (int j = 0; j < 8; ++j)
            gl_lds16(s + (size_t)j * 8 * 1536, dbase + j * 1024);
        s += 128;
        __syncthreads();
        #pragma unroll
        for (int kc = 0; kc < 2; ++kc) {
            const int xo = kc ? x1 : x0;
            bf16x8 af[4], bfr[4];
            #pragma unroll
            for (int m = 0; m < 4; ++m) af[m] = *(const bf16x8*)(lds + arow + m * 2048 + xo);
            #pragma unroll
            for (int n = 0; n < 4; ++n) bfr[n] = *(const bf16x8*)(lds + brow + n * 2048 + xo);
            #pragma unroll
            for (int m = 0; m < 4; ++m)
                #pragma unroll
                for (int n = 0; n < 4; ++n)
                    acc[m][n] = __builtin_amdgcn_mfma_f32_16x16x32_bf16(af[m], bfr[n], acc[m][n], 0, 0, 0);
        }
    }

    const int co = col0 + wc * 64 + ln;
    float bv[4];
    #pragma unroll
    for (int n = 0; n < 4; ++n) bv[n] = bp[co + n * 16];
    #pragma unroll
    for (int m = 0; m < 4; ++m)
        #pragma unroll
        for (int r = 0; r < 4; ++r) {
            int t = row0 + wr * 64 + m * 16 + g * 4 + r;
            #pragma unroll
            for (int n = 0; n < 4; ++n)
                out[(size_t)t * 768 + co + n * 16] = acc[m][n][r] + bv[n];
        }
}

extern "C" void kernel_launch(void* const* d_in, const int* in_sizes, int n_in,
                              void* d_out, int out_size, void* d_ws, size_t ws_size,
                              hipStream_t stream) {
    const float* x     = (const float*)d_in[0];
    const float* Wq    = (const float*)d_in[1];
    const float* bq    = (const float*)d_in[2];
    const float* Wkv   = (const float*)d_in[3];
    const float* bkv   = (const float*)d_in[4];
    const float* Wp    = (const float*)d_in[5];
    const float* bp    = (const float*)d_in[6];
    const float* scale = (const float*)d_in[7];
    float* out = (float*)d_out;

    unsigned short* ws = (unsigned short*)d_ws;
    const size_t SZ = (size_t)4 * 12 * 2048 * 64;     // 6,291,456
    unsigned short* xbw   = ws;
    unsigned short* WqkvT = xbw + SZ;
    unsigned short* WprjT = WqkvT + (size_t)2304 * 768;
    unsigned short* Qw    = WprjT + (size_t)768 * 768;
    unsigned short* Kw    = Qw + SZ;
    unsigned short* Vtw   = Kw + SZ;
    unsigned short* Ow    = Vtw + SZ;

    convx_kernel<<<3072, 256, 0, stream>>>(x, xbw);
    convT_kernel<<<dim3(48, 12), 256, 0, stream>>>(Wq, Wkv, Wp, WqkvT, WprjT);
    qkv_gemm_kernel<<<dim3(18, 64), 256, 0, stream>>>(xbw, WqkvT, bq, bkv, scale, Qw, Kw, Vtw);
    attn_kernel<<<dim3(16, 48), 256, 0, stream>>>(Qw, Kw, Vtw, Ow);
    proj_gemm_kernel<<<dim3(6, 64), 256, 0, stream>>>(Ow, WprjT, bp, out);
}